// Round 1
// baseline (979.048 us; speedup 1.0000x reference)
//
#include <hip/hip_runtime.h>
#include <math.h>

#define NTOK   16384
#define DMODEL 4096
#define NEXP   64
#define WAVES  8                 // K-split factor = waves per block
#define TOKS   64                // tokens per block (lane = token)
#define KTW    16                // k-chunk staged in LDS per wave
#define KPW    (DMODEL / WAVES)  // 512 k per wave
#define NCHUNK (KPW / KTW)       // 32 chunks
#define XSTR   (KTW + 1)         // 17: odd stride -> conflict-free column reads

__global__ __launch_bounds__(WAVES * 64, 1)
void router_kernel(const float* __restrict__ x,
                   const float* __restrict__ W,
                   const float* __restrict__ b,
                   float* __restrict__ out)
{
    // per-wave private x staging: 8 * 64 * 17 * 4B = 34816 B
    __shared__ float xs[WAVES * TOKS * XSTR];
    // logits, transposed [expert][token]: 64*64*4 = 16384 B (stride 64 is
    // conflict-free here because lane index is the fastest-varying dim)
    __shared__ float logits[NEXP * TOKS];

    const int tid  = threadIdx.x;
    const int lane = tid & 63;
    const int wid  = tid >> 6;
    const int t0   = blockIdx.x * TOKS;
    const int kbase = wid * KPW;

    float acc[NEXP];
#pragma unroll
    for (int e = 0; e < NEXP; ++e) acc[e] = 0.f;

    float* xw = xs + wid * (TOKS * XSTR);
    const int lrow = lane >> 2;        // 0..15
    const int lcol = (lane & 3) * 4;   // 0,4,8,12

    for (int c = 0; c < NCHUNK; ++c) {
        const int kc = kbase + c * KTW;

        // stage x[t0..t0+63][kc..kc+15] -> LDS (wave-private, no barrier)
        float4 v[4];
#pragma unroll
        for (int j = 0; j < 4; ++j) {
            const int row = lrow + 16 * j;
            v[j] = *(const float4*)(x + (size_t)(t0 + row) * DMODEL + kc + lcol);
        }
#pragma unroll
        for (int j = 0; j < 4; ++j) {
            const int row = lrow + 16 * j;
            float* dst = xw + row * XSTR + lcol;
            dst[0] = v[j].x; dst[1] = v[j].y; dst[2] = v[j].z; dst[3] = v[j].w;
        }

        // compute: lane = token, 64 expert accumulators
#pragma unroll 4
        for (int kk = 0; kk < KTW; ++kk) {
            const float xv = xw[lane * XSTR + kk];
            const float* wr = W + (size_t)(kc + kk) * NEXP;  // wave-uniform row
#pragma unroll
            for (int e = 0; e < NEXP; ++e)
                acc[e] = fmaf(wr[e], xv, acc[e]);
        }
    }

    // cross-wave reduction into LDS logits[e*64 + token_lane]
    for (int r = 0; r < WAVES; ++r) {
        if (wid == r) {
            if (r == 0) {
#pragma unroll
                for (int e = 0; e < NEXP; ++e) logits[e * TOKS + lane] = acc[e];
            } else {
#pragma unroll
                for (int e = 0; e < NEXP; ++e) logits[e * TOKS + lane] += acc[e];
            }
        }
        __syncthreads();
    }

    // epilogue: wave 0, one token per lane
    if (wid == 0) {
        const int t = t0 + lane;
        float l[NEXP];
        float m = -INFINITY;
#pragma unroll
        for (int e = 0; e < NEXP; ++e) {
            l[e] = logits[e * TOKS + lane] + b[e];
            m = fmaxf(m, l[e]);
        }
        float Z = 0.f;
#pragma unroll
        for (int e = 0; e < NEXP; ++e) {
            l[e] = expf(l[e] - m);
            Z += l[e];
        }
        // top-2 over probs, ties -> lower index (jax.lax.top_k semantics)
        float p1 = -1.f, p2 = -1.f;
        int i1 = 0, i2 = 0;
#pragma unroll
        for (int e = 0; e < NEXP; ++e) {
            const float p = l[e] / Z;
            if (p > p1) { p2 = p1; i2 = i1; p1 = p; i1 = e; }
            else if (p > p2) { p2 = p; i2 = e; }
        }
        const float s = p1 + p2;
        out[2 * t]     = p1 / s;
        out[2 * t + 1] = p2 / s;
        // indices written as float: harness reads the whole output as f32
        out[2 * NTOK + 2 * t]     = (float)i1;
        out[2 * NTOK + 2 * t + 1] = (float)i2;
    }
}

extern "C" void kernel_launch(void* const* d_in, const int* in_sizes, int n_in,
                              void* d_out, int out_size, void* d_ws, size_t ws_size,
                              hipStream_t stream) {
    const float* x = (const float*)d_in[0];
    const float* W = (const float*)d_in[1];
    const float* b = (const float*)d_in[2];
    float* out = (float*)d_out;
    router_kernel<<<dim3(NTOK / TOKS), dim3(WAVES * 64), 0, stream>>>(x, W, b, out);
}

// Round 2
// 605.105 us; speedup vs baseline: 1.6180x; 1.6180x over previous
//
#include <hip/hip_runtime.h>
#include <math.h>

#define NTOK   16384
#define DMODEL 4096
#define NEXP   64
#define WAVES  8                 // K-split factor = waves per block
#define TOKS   64                // tokens per block (lane = token)
#define KPW    (DMODEL / WAVES)  // 512 k per wave
#define KT     32                // k per chunk: 128 B contiguous per lane
#define NCHUNK (KPW / KT)        // 16 chunks

__global__ __launch_bounds__(WAVES * 64, 1)
void router_kernel(const float* __restrict__ x,
                   const float* __restrict__ W,
                   const float* __restrict__ b,
                   float* __restrict__ out)
{
    // logits, transposed [expert][token]
    __shared__ float logits[NEXP * TOKS];

    const int tid  = threadIdx.x;
    const int lane = tid & 63;
    const int wid  = tid >> 6;
    const int t0   = blockIdx.x * TOKS;

    // Assert wave-uniformity of the K-slab offset so W loads become s_load_*.
    // (wid is formally divergent to the compiler; readfirstlane scalarizes it.)
    const int kb = __builtin_amdgcn_readfirstlane(wid * KPW);

    const float* wbase = W + (size_t)kb * NEXP;                    // uniform
    const float* xrow  = x + (size_t)(t0 + lane) * DMODEL + kb;    // per-lane

    float acc[NEXP];
#pragma unroll
    for (int e = 0; e < NEXP; ++e) acc[e] = 0.f;

    for (int c = 0; c < NCHUNK; ++c) {
        // 32 contiguous floats (one full 128B cacheline) per lane
        float4 xv4[KT / 4];
#pragma unroll
        for (int j = 0; j < KT / 4; ++j)
            xv4[j] = *(const float4*)(xrow + c * KT + j * 4);
        const float* xv = (const float*)xv4;

#pragma unroll 8
        for (int kk = 0; kk < KT; ++kk) {
            const float* wr = wbase + (size_t)(c * KT + kk) * NEXP; // uniform
#pragma unroll
            for (int e = 0; e < NEXP; ++e)
                acc[e] = fmaf(wr[e], xv[kk], acc[e]);   // v_fmac s,v
        }
    }

    // cross-wave reduction into LDS logits[e*64 + token_lane]
    for (int r = 0; r < WAVES; ++r) {
        if (wid == r) {
            if (r == 0) {
#pragma unroll
                for (int e = 0; e < NEXP; ++e) logits[e * TOKS + lane] = acc[e];
            } else {
#pragma unroll
                for (int e = 0; e < NEXP; ++e) logits[e * TOKS + lane] += acc[e];
            }
        }
        __syncthreads();
    }

    // epilogue: wave 0, one token per lane
    if (wid == 0) {
        const int t = t0 + lane;
        float l[NEXP];
        float m = -INFINITY;
#pragma unroll
        for (int e = 0; e < NEXP; ++e) {
            l[e] = logits[e * TOKS + lane] + b[e];
            m = fmaxf(m, l[e]);
        }
        float Z = 0.f;
#pragma unroll
        for (int e = 0; e < NEXP; ++e) {
            l[e] = expf(l[e] - m);
            Z += l[e];
        }
        // top-2 over probs, ties -> lower index (jax.lax.top_k semantics)
        float p1 = -1.f, p2 = -1.f;
        int i1 = 0, i2 = 0;
#pragma unroll
        for (int e = 0; e < NEXP; ++e) {
            const float p = l[e] / Z;
            if (p > p1) { p2 = p1; i2 = i1; p1 = p; i1 = e; }
            else if (p > p2) { p2 = p; i2 = e; }
        }
        const float s = p1 + p2;
        out[2 * t]     = p1 / s;
        out[2 * t + 1] = p2 / s;
        // indices written as float: harness reads the whole output as f32
        out[2 * NTOK + 2 * t]     = (float)i1;
        out[2 * NTOK + 2 * t + 1] = (float)i2;
    }
}

extern "C" void kernel_launch(void* const* d_in, const int* in_sizes, int n_in,
                              void* d_out, int out_size, void* d_ws, size_t ws_size,
                              hipStream_t stream) {
    const float* x = (const float*)d_in[0];
    const float* W = (const float*)d_in[1];
    const float* b = (const float*)d_in[2];
    float* out = (float*)d_out;
    router_kernel<<<dim3(NTOK / TOKS), dim3(WAVES * 64), 0, stream>>>(x, W, b, out);
}

// Round 3
// 530.519 us; speedup vs baseline: 1.8455x; 1.1406x over previous
//
#include <hip/hip_runtime.h>
#include <math.h>

#define NTOK   16384
#define DMODEL 4096
#define NEXP   64
#define WAVES  8                 // K-split factor = waves per block
#define TOKS   64                // tokens per block (lane = token)
#define KPW    (DMODEL / WAVES)  // 512 k per wave
#define KT     32                // k per chunk: 128 B contiguous per lane
#define NCHUNK (KPW / KT)        // 16 chunks

#define LD4(p) (*(const float4*)(p))

// one k-step: 64 FMAs, W row via wave-uniform (scalar) loads
#define FMA_K(vv, kk) do {                                   \
    const float* wr = wbase + (size_t)(kk) * NEXP;           \
    _Pragma("unroll")                                        \
    for (int e = 0; e < NEXP; ++e)                           \
        acc[e] = fmaf(wr[e], (vv), acc[e]);                  \
} while (0)

#define DO4(q, kc) do {                                      \
    FMA_K((q).x, (kc) + 0);                                  \
    FMA_K((q).y, (kc) + 1);                                  \
    FMA_K((q).z, (kc) + 2);                                  \
    FMA_K((q).w, (kc) + 3);                                  \
} while (0)

__global__ __launch_bounds__(WAVES * 64, 2)
void router_kernel(const float* __restrict__ x,
                   const float* __restrict__ W,
                   const float* __restrict__ b,
                   float* __restrict__ out)
{
    // logits, transposed [expert][token]
    __shared__ float logits[NEXP * TOKS];

    const int tid  = threadIdx.x;
    const int lane = tid & 63;
    const int wid  = tid >> 6;
    const int t0   = blockIdx.x * TOKS;

    // wave-uniform K-slab offset -> W loads become s_load_*
    const int kb = __builtin_amdgcn_readfirstlane(wid * KPW);

    const float* wbase = W + (size_t)kb * NEXP;                    // uniform
    const float* xrow  = x + (size_t)(t0 + lane) * DMODEL + kb;    // per-lane

    float acc[NEXP];
#pragma unroll
    for (int e = 0; e < NEXP; ++e) acc[e] = 0.f;

    // named-register x buffer (NO private arrays / pointer casts -> no scratch)
    float4 c0 = LD4(xrow + 0),  c1 = LD4(xrow + 4),
           c2 = LD4(xrow + 8),  c3 = LD4(xrow + 12),
           c4 = LD4(xrow + 16), c5 = LD4(xrow + 20),
           c6 = LD4(xrow + 24), c7 = LD4(xrow + 28);

    for (int c = 0; c < NCHUNK - 1; ++c) {
        const float* nx = xrow + (c + 1) * KT;
        // prefetch next chunk while computing current
        float4 n0 = LD4(nx + 0),  n1 = LD4(nx + 4),
               n2 = LD4(nx + 8),  n3 = LD4(nx + 12),
               n4 = LD4(nx + 16), n5 = LD4(nx + 20),
               n6 = LD4(nx + 24), n7 = LD4(nx + 28);
        const int kc = c * KT;
        DO4(c0, kc + 0);  DO4(c1, kc + 4);
        DO4(c2, kc + 8);  DO4(c3, kc + 12);
        DO4(c4, kc + 16); DO4(c5, kc + 20);
        DO4(c6, kc + 24); DO4(c7, kc + 28);
        c0 = n0; c1 = n1; c2 = n2; c3 = n3;
        c4 = n4; c5 = n5; c6 = n6; c7 = n7;
    }
    {
        const int kc = (NCHUNK - 1) * KT;
        DO4(c0, kc + 0);  DO4(c1, kc + 4);
        DO4(c2, kc + 8);  DO4(c3, kc + 12);
        DO4(c4, kc + 16); DO4(c5, kc + 20);
        DO4(c6, kc + 24); DO4(c7, kc + 28);
    }

    // cross-wave reduction into LDS logits[e*64 + token_lane]
    for (int r = 0; r < WAVES; ++r) {
        if (wid == r) {
            if (r == 0) {
#pragma unroll
                for (int e = 0; e < NEXP; ++e) logits[e * TOKS + lane] = acc[e];
            } else {
#pragma unroll
                for (int e = 0; e < NEXP; ++e) logits[e * TOKS + lane] += acc[e];
            }
        }
        __syncthreads();
    }

    // epilogue: wave 0, one token per lane
    if (wid == 0) {
        const int t = t0 + lane;
        float l[NEXP];
        float m = -INFINITY;
#pragma unroll
        for (int e = 0; e < NEXP; ++e) {
            l[e] = logits[e * TOKS + lane] + b[e];
            m = fmaxf(m, l[e]);
        }
        float Z = 0.f;
#pragma unroll
        for (int e = 0; e < NEXP; ++e) {
            l[e] = expf(l[e] - m);
            Z += l[e];
        }
        // top-2 over probs, ties -> lower index (jax.lax.top_k semantics)
        float p1 = -1.f, p2 = -1.f;
        int i1 = 0, i2 = 0;
#pragma unroll
        for (int e = 0; e < NEXP; ++e) {
            const float p = l[e] / Z;
            if (p > p1) { p2 = p1; i2 = i1; p1 = p; i1 = e; }
            else if (p > p2) { p2 = p; i2 = e; }
        }
        const float s = p1 + p2;
        out[2 * t]     = p1 / s;
        out[2 * t + 1] = p2 / s;
        // indices written as float: harness reads the whole output as f32
        out[2 * NTOK + 2 * t]     = (float)i1;
        out[2 * NTOK + 2 * t + 1] = (float)i2;
    }
}

extern "C" void kernel_launch(void* const* d_in, const int* in_sizes, int n_in,
                              void* d_out, int out_size, void* d_ws, size_t ws_size,
                              hipStream_t stream) {
    const float* x = (const float*)d_in[0];
    const float* W = (const float*)d_in[1];
    const float* b = (const float*)d_in[2];
    float* out = (float*)d_out;
    router_kernel<<<dim3(NTOK / TOKS), dim3(WAVES * 64), 0, stream>>>(x, W, b, out);
}